// Round 8
// baseline (403.937 us; speedup 1.0000x reference)
//
#include <hip/hip_runtime.h>
#include <math.h>

#define SQRT8_INV  0.35355339059327373f   // 1/sqrt(8)
#define H_SCALE    0.04419417382415922f   // 0.25/sqrt(32)
#define FAN_SC     0.04419417382415922f   // 1/sqrt(32*16)
#define W1_SCALE   0.125f                 // 1/sqrt(64)
#define LIN2_SCALE 0.125f                 // 1/sqrt(64)
#define SQ3_INVF   0.57735026918962576f   // 1/sqrt(3)

// record layout per sorted edge slot: 272 B = 68 uints
//   [0..63]  w-words: word j = pack_bf16(w[j], w[j+64]),  j = 0..63
//   [64..67] eattr float4
#define REC_U 68
#define REC_B 272

typedef __attribute__((ext_vector_type(8))) short short8;
typedef __attribute__((ext_vector_type(4))) float f32x4;

__device__ __forceinline__ unsigned pack_bf16(float a, float b) {
    unsigned ua = __float_as_uint(a);
    ua += 0x7FFFu + ((ua >> 16) & 1u);          // RNE
    unsigned ub = __float_as_uint(b);
    ub += 0x7FFFu + ((ub >> 16) & 1u);
    return (ua >> 16) | (ub & 0xFFFF0000u);
}
__device__ __forceinline__ short bf16b(float x) {
    unsigned u = __float_as_uint(x);
    u += 0x7FFFu + ((u >> 16) & 1u);
    return (short)(u >> 16);
}
__device__ __forceinline__ float bf_lo(unsigned u) { return __uint_as_float(u << 16); }
__device__ __forceinline__ float bf_hi(unsigned u) { return __uint_as_float(u & 0xFFFF0000u); }

// ---------------- zero int buffer ----------------
__global__ __launch_bounds__(256) void zero_int(int* __restrict__ p, int n) {
    int i = blockIdx.x * 256 + threadIdx.x;
    if (i < n) p[i] = 0;
}

// ---------------- w1 -> w1p (fallback gather path) ----------------
__global__ __launch_bounds__(256) void prep_w1p(const float* __restrict__ w1,
                                                float* __restrict__ w1p) {
    int idx = blockIdx.x * 256 + threadIdx.x;
    if (idx >= 64 * 64) return;
    int j = idx >> 6, t = idx & 63;
    int colA = (t < 32) ? t : t + 32;
    int colB = (t < 32) ? t + 32 : t + 64;
    w1p[idx * 2 + 0] = w1[j * 128 + colA];
    w1p[idx * 2 + 1] = w1[j * 128 + colB];
}

// ---------------- histogram of edge_dst ----------------
__global__ __launch_bounds__(256) void hist_kernel(const int* __restrict__ eidx,
                                                   int* __restrict__ cnt, int E) {
    int e = blockIdx.x * 256 + threadIdx.x;
    if (e < E) atomicAdd(&cnt[eidx[e]], 1);
}

// ---------------- hierarchical scan, stage A: per-block sums ----------------
__global__ __launch_bounds__(256) void scan_bsum(const int* __restrict__ cnt,
                                                 int* __restrict__ bsum, int N) {
    __shared__ int red[256];
    int t = threadIdx.x, i = blockIdx.x * 256 + t;
    red[t] = (i < N) ? cnt[i] : 0;
    __syncthreads();
    #pragma unroll
    for (int d = 128; d > 0; d >>= 1) {
        if (t < d) red[t] += red[t + d];
        __syncthreads();
    }
    if (t == 0) bsum[blockIdx.x] = red[0];
}

// ---------------- stage B: exclusive scan of block sums (nb <= 1024) ----------------
__global__ __launch_bounds__(1024) void scan_bscan(int* __restrict__ bsum, int nb) {
    __shared__ int s[1024];
    int t = threadIdx.x;
    int v = (t < nb) ? bsum[t] : 0;
    s[t] = v;
    __syncthreads();
    for (int d = 1; d < 1024; d <<= 1) {
        int u = (t >= d) ? s[t - d] : 0;
        __syncthreads();
        s[t] += u;
        __syncthreads();
    }
    if (t < nb) bsum[t] = s[t] - v;   // exclusive
}

// ---------------- stage C: in-block scan + base -> off, cur ----------------
__global__ __launch_bounds__(256) void scan_final(const int* __restrict__ cnt,
                                                  const int* __restrict__ bsum,
                                                  int* __restrict__ off,
                                                  int* __restrict__ cur, int N) {
    __shared__ int s[256];
    int t = threadIdx.x, i = blockIdx.x * 256 + t;
    int v = (i < N) ? cnt[i] : 0;
    s[t] = v;
    __syncthreads();
    for (int d = 1; d < 256; d <<= 1) {
        int u = (t >= d) ? s[t - d] : 0;
        __syncthreads();
        s[t] += u;
        __syncthreads();
    }
    int ex = s[t] - v + bsum[blockIdx.x];
    if (i < N) { off[i] = ex; cur[i] = ex; }
    if (i == N - 1) off[N] = ex + v;
}

// ---------------- scatter edge ids + srcs + dsts into dst-sorted order ----------------
__global__ __launch_bounds__(256) void scatter_kernel(const int* __restrict__ eidx,
                                                      int* __restrict__ cur,
                                                      int* __restrict__ order,
                                                      int* __restrict__ srcs,
                                                      int* __restrict__ dsts, int E) {
    int e = blockIdx.x * 256 + threadIdx.x;
    if (e >= E) return;
    int d = eidx[e];
    int pos = atomicAdd(&cur[d], 1);
    order[pos] = e;
    srcs[pos] = eidx[E + e];
    dsts[pos] = d;
}

// ---------------- node stage: h (lin1, interleaved float4) + sc into out ----------------
__global__ __launch_bounds__(128) void node_kernel(
    const float* __restrict__ nf, const float* __restrict__ attrs,
    const float* __restrict__ l1w0, const float* __restrict__ l1w1,
    const float* __restrict__ scw0, const float* __restrict__ scw1,
    float* __restrict__ h4, float* __restrict__ out) {
    int n = blockIdx.x;
    int t = threadIdx.x;
    __shared__ float x[128];
    __shared__ int vs;
    x[t] = nf[n * 128 + t];
    if (t < 16) {
        if (attrs[n * 16 + t] > 0.5f) vs = t;   // one-hot: exactly one writer
    }
    __syncthreads();
    int v = vs;
    if (t < 32) {
        int w = t;
        float a = 0.f, b = 0.f;
        #pragma unroll
        for (int u = 0; u < 32; ++u) {
            float xv = x[u];
            a = fmaf(xv, l1w0[u * 32 + w], a);
            b = fmaf(xv, scw0[u * 512 + v * 32 + w], b);
        }
        h4[n * 128 + w * 4] = a * H_SCALE;
        out[n * 128 + w]    = b * FAN_SC;
    } else {
        int j = t - 32;                // 0..95
        int vch = j / 3, m = j - vch * 3;
        float a = 0.f, b = 0.f;
        #pragma unroll
        for (int u = 0; u < 32; ++u) {
            float xv = x[32 + u * 3 + m];
            a = fmaf(xv, l1w1[u * 32 + vch], a);
            b = fmaf(xv, scw1[u * 512 + v * 32 + vch], b);
        }
        h4[n * 128 + vch * 4 + 1 + m]   = a * H_SCALE;
        out[n * 128 + 32 + vch * 3 + m] = b * FAN_SC;
    }
}

// ---------------- edge MLP: layer1 VALU (chunked) + layer2 MFMA ----------------
__global__ __launch_bounds__(256) void mlp_kernel(
    const float* __restrict__ ee, const float4* __restrict__ eattr4,
    const int* __restrict__ order,
    const float* __restrict__ w0, const float* __restrict__ w1,
    unsigned* __restrict__ rec, int base, int len) {
    __shared__ unsigned amat[256 * 32];     // A-tile: [edge][64 bf16], XOR-swizzled
    int tid  = threadIdx.x;
    int lane = tid & 63, wid = tid >> 6;
    int m = lane & 15, q = lane >> 4;
    int idx  = blockIdx.x * 256 + tid;
    bool valid = idx < len;

    // ---- B fragments (once per block): bf16(w1[k][chan]), k-chunk q*8+i
    short8 bf00, bf01, bf10, bf11;          // [chan tile lo/hi][k-step 0/1]
    {
        int clo = wid * 16 + m, chi = clo + 64;
        #pragma unroll
        for (int i = 0; i < 8; ++i) {
            int k0 = q * 8 + i, k1 = 32 + q * 8 + i;
            bf00[i] = bf16b(w1[k0 * 128 + clo]);
            bf01[i] = bf16b(w1[k1 * 128 + clo]);
            bf10[i] = bf16b(w1[k0 * 128 + chi]);
            bf11[i] = bf16b(w1[k1 * 128 + chi]);
        }
    }

    // ---- gather edge embedding + eattr (issued together, one latency)
    float4 ea = make_float4(0.f, 0.f, 0.f, 0.f);
    float eev[8] = {0.f,0.f,0.f,0.f,0.f,0.f,0.f,0.f};
    if (valid) {
        int e = order[base + idx];
        ea  = eattr4[e];
        const float4* eep = (const float4*)ee;
        float4 e0 = eep[(size_t)e * 2], e1 = eep[(size_t)e * 2 + 1];
        eev[0] = e0.x * SQRT8_INV; eev[1] = e0.y * SQRT8_INV;
        eev[2] = e0.z * SQRT8_INV; eev[3] = e0.w * SQRT8_INV;
        eev[4] = e1.x * SQRT8_INV; eev[5] = e1.y * SQRT8_INV;
        eev[6] = e1.z * SQRT8_INV; eev[7] = e1.w * SQRT8_INV;
    }

    // ---- layer 1 + silu in chunks of 8, pack + stage immediately (low VGPR)
    {
        char* arow = (char*)(amat + tid * 32);
        #pragma unroll
        for (int kc = 0; kc < 8; ++kc) {
            float h[8];
            #pragma unroll
            for (int jj = 0; jj < 8; ++jj) {
                int j = kc * 8 + jj;
                float a = 0.f;
                #pragma unroll
                for (int k = 0; k < 8; ++k) a = fmaf(eev[k], w0[k * 64 + j], a);
                float s = 1.f / (1.f + __expf(-a));
                h[jj] = a * s * W1_SCALE;
            }
            uint4 v = make_uint4(pack_bf16(h[0], h[1]), pack_bf16(h[2], h[3]),
                                 pack_bf16(h[4], h[5]), pack_bf16(h[6], h[7]));
            if (!valid) v = make_uint4(0u, 0u, 0u, 0u);
            *(uint4*)(arow + ((kc * 16) ^ ((tid & 7) << 4))) = v;
        }
    }
    __syncthreads();

    // ---- MFMA: 16 edge-tiles x (lo,hi chan tiles) x K=64
    int jb = wid * 16;
    int blockbase = blockIdx.x * 256;
    for (int et = 0; et < 16; ++et) {
        int row = et * 16 + m;
        const char* abase = (const char*)(amat + row * 32);
        int swz = (row & 7) << 4;
        short8 a0 = *(const short8*)(abase + ((q * 16) ^ swz));
        short8 a1 = *(const short8*)(abase + (((64 + q * 16)) ^ swz));
        f32x4 dlo = {0.f, 0.f, 0.f, 0.f}, dhi = {0.f, 0.f, 0.f, 0.f};
        dlo = __builtin_amdgcn_mfma_f32_16x16x32_bf16(a0, bf00, dlo, 0, 0, 0);
        dlo = __builtin_amdgcn_mfma_f32_16x16x32_bf16(a1, bf01, dlo, 0, 0, 0);
        dhi = __builtin_amdgcn_mfma_f32_16x16x32_bf16(a0, bf10, dhi, 0, 0, 0);
        dhi = __builtin_amdgcn_mfma_f32_16x16x32_bf16(a1, bf11, dhi, 0, 0, 0);
        // D: row(edge-within-tile) = 4*q + i, col(word) = jb + m
        #pragma unroll
        for (int i = 0; i < 4; ++i) {
            int eloc = blockbase + et * 16 + 4 * q + i;
            if (eloc < len)
                rec[(size_t)eloc * REC_U + jb + m] = pack_bf16(dlo[i], dhi[i]);
        }
    }

    // ---- tail field (eattr)
    if (valid) {
        unsigned* myrec = rec + (size_t)idx * REC_U;
        *(float4*)(myrec + 64) = ea;
    }
}

// ---------------- window reduce: 64-edge windows, segmented flush, no atomics ----
__global__ __launch_bounds__(256) void wred_kernel(
    const unsigned* __restrict__ rec, const int* __restrict__ off,
    const int* __restrict__ srcs, const int* __restrict__ dsts,
    const float4* __restrict__ h4, float* __restrict__ mn,
    float* __restrict__ sb, int base, int len) {
    int wid = threadIdx.x >> 6, t = threadIdx.x & 63;
    int win = blockIdx.x * 4 + wid;        // window index within segment
    int wbeg = win * 64;                   // local segment edge index
    if (wbeg >= len) return;
    int cnt = min(64, len - wbeg);
    int gbeg = base + wbeg;                // global sorted index of window start
    int gend = gbeg + cnt;
    int gwin = gbeg >> 6;                  // global window id (base % 256 == 0)
    int c = t & 31, half = t >> 5;
    int kk = half ? c + 32 : c;
    int srcv = (t < cnt) ? srcs[gbeg + t] : 0;
    int dstv = (t < cnt) ? dsts[gbeg + t] : -1;
    float acc0 = 0.f, acc1 = 0.f, acc2 = 0.f, acc3 = 0.f;

#define REFILL(k, ii) do {                                              \
        int _i = (ii);                                                  \
        if (_i < cnt) {                                                 \
            const unsigned* _r = rec + (size_t)(wbeg + _i) * REC_U;     \
            wu##k = _r[kk];                                             \
            ea##k = *(const float4*)(_r + 64);                          \
            int _s = __builtin_amdgcn_readlane(srcv, _i);               \
            xs##k = h4[(size_t)_s * 32 + c];                            \
        }                                                               \
    } while (0)

#define COMPUTE(k) do {                                                 \
        float wlo = bf_lo(wu##k), whi = bf_hi(wu##k);                   \
        float4 _ea = ea##k, _xs = xs##k;                                \
        if (half == 0) {                                                \
            acc0 = fmaf(wlo * _xs.x, _ea.x, acc0);       /* m0a */      \
            float cy = whi * _ea.x;                                     \
            acc1 = fmaf(cy, _xs.y, acc1);                /* m1b */      \
            acc2 = fmaf(cy, _xs.z, acc2);                               \
            acc3 = fmaf(cy, _xs.w, acc3);                               \
        } else {                                                        \
            float bx = wlo * _xs.x;                                     \
            acc1 = fmaf(bx, _ea.y, acc1);                /* m1a */      \
            acc2 = fmaf(bx, _ea.z, acc2);                               \
            acc3 = fmaf(bx, _ea.w, acc3);                               \
            float dv = _xs.y * _ea.y + _xs.z * _ea.z + _xs.w * _ea.w;   \
            acc0 = fmaf(whi * SQ3_INVF, dv, acc0);       /* m0b */      \
        }                                                               \
    } while (0)

#define FLUSH(ii) do {                                                  \
        int _n = __builtin_amdgcn_readlane(dstv, (ii));                 \
        bool _cs = off[_n] < gbeg;                                      \
        bool _ce = off[_n + 1] > gend;                                  \
        float* _dp = (!_cs && !_ce) ? (mn + (size_t)_n * 256)           \
                   : (sb + ((size_t)gwin * 2 + (_cs ? 0 : 1)) * 256);   \
        if (half == 0) {                                                \
            _dp[c] = acc0;                                              \
            _dp[160 + 3*c + 0] = acc1;                                  \
            _dp[160 + 3*c + 1] = acc2;                                  \
            _dp[160 + 3*c + 2] = acc3;                                  \
        } else {                                                        \
            _dp[32 + c] = acc0;                                         \
            _dp[64 + 3*c + 0] = acc1;                                   \
            _dp[64 + 3*c + 1] = acc2;                                   \
            _dp[64 + 3*c + 2] = acc3;                                   \
        }                                                               \
        acc0 = acc1 = acc2 = acc3 = 0.f;                                \
    } while (0)

#define BND(ii) do {                                                    \
        int _j = (ii);                                                  \
        bool _bf = (_j == cnt - 1) ||                                   \
            (__builtin_amdgcn_readlane(dstv, _j) !=                     \
             __builtin_amdgcn_readlane(dstv, _j + 1));                  \
        if (_bf) FLUSH(_j);                                             \
    } while (0)

    unsigned wu0 = 0, wu1 = 0, wu2 = 0, wu3 = 0;
    float4 ea0 = make_float4(0,0,0,0), ea1 = ea0, ea2 = ea0, ea3 = ea0;
    float4 xs0 = ea0, xs1 = ea0, xs2 = ea0, xs3 = ea0;
    REFILL(0, 0); REFILL(1, 1); REFILL(2, 2); REFILL(3, 3);
    int i = 0;
    for (; i + 4 <= cnt; i += 4) {
        COMPUTE(0); BND(i + 0); REFILL(0, i + 4);
        COMPUTE(1); BND(i + 1); REFILL(1, i + 5);
        COMPUTE(2); BND(i + 2); REFILL(2, i + 6);
        COMPUTE(3); BND(i + 3); REFILL(3, i + 7);
    }
    int rem = cnt - i;
    if (rem > 0) { COMPUTE(0); BND(i + 0); }
    if (rem > 1) { COMPUTE(1); BND(i + 1); }
    if (rem > 2) { COMPUTE(2); BND(i + 2); }
#undef REFILL
#undef COMPUTE
#undef FLUSH
#undef BND
}

// ---------------- fixup + lin2: combine mn / sideband partials, write out ----------
__global__ __launch_bounds__(256) void fixlin_kernel(
    const float* __restrict__ mn, const float* __restrict__ sb,
    const int* __restrict__ off,
    const float* __restrict__ l2w0, const float* __restrict__ l2w1,
    float* __restrict__ out, int N) {
    int w = threadIdx.x >> 6, t = threadIdx.x & 63;
    int n = blockIdx.x * 4 + w;
    __shared__ float ld[4][256];
    int c = t & 31, half = t >> 5;
    bool has = false;
    if (n < N) {
        int b = off[n], e = off[n + 1];
        if (e > b) {
            has = true;
            int w0 = b >> 6, w1 = (e - 1) >> 6;
            int p0 = half ? 32 + c : c;
            int p1 = half ? 64 + 3 * c : 160 + 3 * c;
            float v0, v1, v2, v3;
            if (w0 == w1) {
                const float* r = mn + (size_t)n * 256;   // interior: direct row
                v0 = r[p0]; v1 = r[p1]; v2 = r[p1 + 1]; v3 = r[p1 + 2];
            } else {
                const float* r = sb + ((size_t)w0 * 2 + 1) * 256;  // tail of w0
                v0 = r[p0]; v1 = r[p1]; v2 = r[p1 + 1]; v3 = r[p1 + 2];
                for (int ww = w0 + 1; ww <= w1; ++ww) {            // slot0 of rest
                    const float* q = sb + ((size_t)ww * 2) * 256;
                    v0 += q[p0]; v1 += q[p1]; v2 += q[p1 + 1]; v3 += q[p1 + 2];
                }
            }
            ld[w][p0] = v0;
            ld[w][p1] = v1; ld[w][p1 + 1] = v2; ld[w][p1 + 2] = v3;
        }
    }
    __syncthreads();
    if (n < N && has) {
        #pragma unroll
        for (int hh = 0; hh < 2; ++hh) {
            int j = t + hh * 64;
            float acc = 0.f;
            if (j < 32) {
                #pragma unroll
                for (int u = 0; u < 64; ++u) acc = fmaf(ld[w][u], l2w0[u * 32 + j], acc);
            } else {
                int jj = j - 32, vch = jj / 3, m = jj - vch * 3;
                #pragma unroll
                for (int u = 0; u < 64; ++u) acc = fmaf(ld[w][64 + u * 3 + m], l2w1[u * 32 + vch], acc);
            }
            out[(size_t)n * 128 + j] += acc * LIN2_SCALE;
        }
    }
}

// ---------------- FALLBACK (ws too small): round-2 fused gather ----------------
__global__ __launch_bounds__(64) void gather_kernel(
    const float* __restrict__ ee, const float4* __restrict__ eattr4,
    const int* __restrict__ eidx, const int* __restrict__ order,
    const int* __restrict__ off,
    const float* __restrict__ w0, const float2* __restrict__ w1p2,
    const float4* __restrict__ h4,
    const float* __restrict__ l2w0, const float* __restrict__ l2w1,
    float* __restrict__ out, int E) {
    int n = blockIdx.x, t = threadIdx.x;
    int beg = off[n], end = off[n + 1];
    __shared__ float s_ee[8];
    __shared__ float s_hid[64];
    __shared__ float ld[256];
    float acc0 = 0.f, acc1 = 0.f, acc2 = 0.f, acc3 = 0.f;
    int c = t & 31;
    for (int i = beg; i < end; ++i) {
        int e = order[i];
        int src = eidx[E + e];
        if (t < 8) s_ee[t] = ee[e * 8 + t] * SQRT8_INV;
        __syncthreads();
        float a = 0.f;
        #pragma unroll
        for (int k = 0; k < 8; ++k) a = fmaf(s_ee[k], w0[k * 64 + t], a);
        float sg = 1.f / (1.f + __expf(-a));
        __syncthreads();
        s_hid[t] = a * sg * W1_SCALE;
        __syncthreads();
        float wA = 0.f, wB = 0.f;
        #pragma unroll
        for (int j = 0; j < 64; ++j) {
            float2 wv = w1p2[j * 64 + t];
            float hj = s_hid[j];
            wA = fmaf(hj, wv.x, wA);
            wB = fmaf(hj, wv.y, wB);
        }
        float4 xs = h4[(size_t)src * 32 + c];
        float4 ea = eattr4[e];
        if (t < 32) {
            acc0 = fmaf(wA * xs.x, ea.x, acc0);
            float bx = wB * xs.x;
            acc1 = fmaf(bx, ea.y, acc1);
            acc2 = fmaf(bx, ea.z, acc2);
            acc3 = fmaf(bx, ea.w, acc3);
        } else {
            float dv = xs.y * ea.y + xs.z * ea.z + xs.w * ea.w;
            acc0 = fmaf(wB * SQ3_INVF, dv, acc0);
            float cy = wA * ea.x;
            acc1 = fmaf(cy, xs.y, acc1);
            acc2 = fmaf(cy, xs.z, acc2);
            acc3 = fmaf(cy, xs.w, acc3);
        }
    }
    if (t < 32) {
        ld[t] = acc0;
        ld[64 + t * 3 + 0] = acc1;
        ld[64 + t * 3 + 1] = acc2;
        ld[64 + t * 3 + 2] = acc3;
    } else {
        int cc = t - 32;
        ld[32 + cc] = acc0;
        ld[160 + cc * 3 + 0] = acc1;
        ld[160 + cc * 3 + 1] = acc2;
        ld[160 + cc * 3 + 2] = acc3;
    }
    __syncthreads();
    #pragma unroll
    for (int hh = 0; hh < 2; ++hh) {
        int j = t + hh * 64;
        float acc = 0.f;
        if (j < 32) {
            #pragma unroll
            for (int u = 0; u < 64; ++u) acc = fmaf(ld[u], l2w0[u * 32 + j], acc);
        } else {
            int jj = j - 32, vch = jj / 3, m = jj - vch * 3;
            #pragma unroll
            for (int u = 0; u < 64; ++u) acc = fmaf(ld[64 + u * 3 + m], l2w1[u * 32 + vch], acc);
        }
        out[(size_t)n * 128 + j] += acc * LIN2_SCALE;
    }
}

extern "C" void kernel_launch(void* const* d_in, const int* in_sizes, int n_in,
                              void* d_out, int out_size, void* d_ws, size_t ws_size,
                              hipStream_t stream) {
    const float* nf    = (const float*)d_in[0];
    const float* attrs = (const float*)d_in[1];
    const float* eattr = (const float*)d_in[2];
    const float* ee    = (const float*)d_in[3];
    const int*   eidx  = (const int*)d_in[4];
    const float* l1w0  = (const float*)d_in[5];
    const float* l1w1  = (const float*)d_in[6];
    const float* w0    = (const float*)d_in[7];
    const float* w1    = (const float*)d_in[8];
    const float* l2w0  = (const float*)d_in[9];
    const float* l2w1  = (const float*)d_in[10];
    const float* scw0  = (const float*)d_in[11];
    const float* scw1  = (const float*)d_in[12];

    int N = in_sizes[0] / 128;
    int E = in_sizes[3] / 8;
    int nb = (N + 255) / 256;
    int nw = (E + 63) / 64;

    // ws layout: h4 | w1p | cnt | off | cur | bsum | order | srcs | dsts | mn | sb | rec
    float* h4    = (float*)d_ws;                       // N*128
    float* w1p   = h4 + (size_t)N * 128;               // 8192
    int*   cnt   = (int*)(w1p + 8192);                 // N
    int*   off   = cnt + N;                            // N+1
    int*   cur   = off + N + 1;                        // N
    int*   bsum  = cur + N;                            // nb
    int*   order = bsum + nb;                          // E
    int*   srcs  = order + E;                          // E
    int*   dsts  = srcs + E;                           // E
    float* mn    = (float*)(dsts + E);                 // N*256
    float* sb    = mn + (size_t)N * 256;               // nw*512
    size_t rec_off = (((size_t)(sb + (size_t)nw * 512) - (size_t)d_ws) + 255) & ~(size_t)255;
    unsigned* rec = (unsigned*)((char*)d_ws + rec_off);

    bool full = ws_size >= rec_off + (size_t)E * REC_B;
    int L0;
    if (full) {
        L0 = E;
    } else {
        L0 = ((E / 2) + 255) / 256 * 256;
        if (L0 > E) L0 = E;
    }
    int len0 = L0, len1 = E - L0;
    int maxlen = len0 > len1 ? len0 : len1;
    bool big = ws_size >= rec_off + (size_t)maxlen * REC_B;

    zero_int<<<(N + 255) / 256, 256, 0, stream>>>(cnt, N);
    hist_kernel<<<(E + 255) / 256, 256, 0, stream>>>(eidx, cnt, E);
    scan_bsum<<<nb, 256, 0, stream>>>(cnt, bsum, N);
    scan_bscan<<<1, 1024, 0, stream>>>(bsum, nb);
    scan_final<<<nb, 256, 0, stream>>>(cnt, bsum, off, cur, N);
    scatter_kernel<<<(E + 255) / 256, 256, 0, stream>>>(eidx, cur, order, srcs, dsts, E);
    node_kernel<<<N, 128, 0, stream>>>(nf, attrs, l1w0, l1w1, scw0, scw1, h4, (float*)d_out);

    if (big) {
        int nwin0 = (len0 + 63) / 64;
        mlp_kernel<<<(len0 + 255) / 256, 256, 0, stream>>>(ee, (const float4*)eattr,
                                                           order, w0, w1, rec, 0, len0);
        wred_kernel<<<(nwin0 + 3) / 4, 256, 0, stream>>>(rec, off, srcs, dsts,
                                                         (const float4*)h4, mn, sb,
                                                         0, len0);
        if (len1 > 0) {
            int nwin1 = (len1 + 63) / 64;
            mlp_kernel<<<(len1 + 255) / 256, 256, 0, stream>>>(ee, (const float4*)eattr,
                                                               order, w0, w1, rec, L0, len1);
            wred_kernel<<<(nwin1 + 3) / 4, 256, 0, stream>>>(rec, off, srcs, dsts,
                                                             (const float4*)h4, mn, sb,
                                                             L0, len1);
        }
        fixlin_kernel<<<(N + 3) / 4, 256, 0, stream>>>(mn, sb, off, l2w0, l2w1,
                                                       (float*)d_out, N);
    } else {
        prep_w1p<<<16, 256, 0, stream>>>(w1, w1p);
        gather_kernel<<<N, 64, 0, stream>>>(ee, (const float4*)eattr, eidx, order, off,
                                            w0, (const float2*)w1p, (const float4*)h4,
                                            l2w0, l2w1, (float*)d_out, E);
    }
}

// Round 9
// 391.300 us; speedup vs baseline: 1.0323x; 1.0323x over previous
//
#include <hip/hip_runtime.h>
#include <math.h>

#define SQRT8_INV  0.35355339059327373f   // 1/sqrt(8)
#define H_SCALE    0.04419417382415922f   // 0.25/sqrt(32)
#define FAN_SC     0.04419417382415922f   // 1/sqrt(32*16)
#define W1_SCALE   0.125f                 // 1/sqrt(64)
#define LIN2_SCALE 0.125f                 // 1/sqrt(64)
#define SQ3_INVF   0.57735026918962576f   // 1/sqrt(3)

typedef __attribute__((ext_vector_type(8))) short short8;
typedef __attribute__((ext_vector_type(4))) float f32x4;

__device__ __forceinline__ unsigned pack_bf16(float a, float b) {
    unsigned ua = __float_as_uint(a);
    ua += 0x7FFFu + ((ua >> 16) & 1u);          // RNE
    unsigned ub = __float_as_uint(b);
    ub += 0x7FFFu + ((ub >> 16) & 1u);
    return (ua >> 16) | (ub & 0xFFFF0000u);
}
__device__ __forceinline__ short bf16b(float x) {
    unsigned u = __float_as_uint(x);
    u += 0x7FFFu + ((u >> 16) & 1u);
    return (short)(u >> 16);
}
__device__ __forceinline__ float bf_lo(unsigned u) { return __uint_as_float(u << 16); }
__device__ __forceinline__ float bf_hi(unsigned u) { return __uint_as_float(u & 0xFFFF0000u); }

// ---------------- zero int buffer ----------------
__global__ __launch_bounds__(256) void zero_int(int* __restrict__ p, int n) {
    int i = blockIdx.x * 256 + threadIdx.x;
    if (i < n) p[i] = 0;
}

// ---------------- w1 -> w1p (fallback gather path) ----------------
__global__ __launch_bounds__(256) void prep_w1p(const float* __restrict__ w1,
                                                float* __restrict__ w1p) {
    int idx = blockIdx.x * 256 + threadIdx.x;
    if (idx >= 64 * 64) return;
    int j = idx >> 6, t = idx & 63;
    int colA = (t < 32) ? t : t + 32;
    int colB = (t < 32) ? t + 32 : t + 64;
    w1p[idx * 2 + 0] = w1[j * 128 + colA];
    w1p[idx * 2 + 1] = w1[j * 128 + colB];
}

// ---------------- histogram of edge_dst ----------------
__global__ __launch_bounds__(256) void hist_kernel(const int* __restrict__ eidx,
                                                   int* __restrict__ cnt, int E) {
    int e = blockIdx.x * 256 + threadIdx.x;
    if (e < E) atomicAdd(&cnt[eidx[e]], 1);
}

// ---------------- hierarchical scan, stage A: per-block sums ----------------
__global__ __launch_bounds__(256) void scan_bsum(const int* __restrict__ cnt,
                                                 int* __restrict__ bsum, int N) {
    __shared__ int red[256];
    int t = threadIdx.x, i = blockIdx.x * 256 + t;
    red[t] = (i < N) ? cnt[i] : 0;
    __syncthreads();
    #pragma unroll
    for (int d = 128; d > 0; d >>= 1) {
        if (t < d) red[t] += red[t + d];
        __syncthreads();
    }
    if (t == 0) bsum[blockIdx.x] = red[0];
}

// ---------------- stage B: exclusive scan of block sums (nb <= 1024) ----------------
__global__ __launch_bounds__(1024) void scan_bscan(int* __restrict__ bsum, int nb) {
    __shared__ int s[1024];
    int t = threadIdx.x;
    int v = (t < nb) ? bsum[t] : 0;
    s[t] = v;
    __syncthreads();
    for (int d = 1; d < 1024; d <<= 1) {
        int u = (t >= d) ? s[t - d] : 0;
        __syncthreads();
        s[t] += u;
        __syncthreads();
    }
    if (t < nb) bsum[t] = s[t] - v;   // exclusive
}

// ---------------- stage C: in-block scan + base -> off, cur ----------------
__global__ __launch_bounds__(256) void scan_final(const int* __restrict__ cnt,
                                                  const int* __restrict__ bsum,
                                                  int* __restrict__ off,
                                                  int* __restrict__ cur, int N) {
    __shared__ int s[256];
    int t = threadIdx.x, i = blockIdx.x * 256 + t;
    int v = (i < N) ? cnt[i] : 0;
    s[t] = v;
    __syncthreads();
    for (int d = 1; d < 256; d <<= 1) {
        int u = (t >= d) ? s[t - d] : 0;
        __syncthreads();
        s[t] += u;
        __syncthreads();
    }
    int ex = s[t] - v + bsum[blockIdx.x];
    if (i < N) { off[i] = ex; cur[i] = ex; }
    if (i == N - 1) off[N] = ex + v;
}

// ---------------- scatter edge ids + srcs + dsts into dst-sorted order ----------------
__global__ __launch_bounds__(256) void scatter_kernel(const int* __restrict__ eidx,
                                                      int* __restrict__ cur,
                                                      int* __restrict__ order,
                                                      int* __restrict__ srcs,
                                                      int* __restrict__ dsts, int E) {
    int e = blockIdx.x * 256 + threadIdx.x;
    if (e >= E) return;
    int d = eidx[e];
    int pos = atomicAdd(&cur[d], 1);
    order[pos] = e;
    srcs[pos] = eidx[E + e];
    dsts[pos] = d;
}

// ---------------- node stage: h (lin1, interleaved float4) + sc into out ----------------
__global__ __launch_bounds__(128) void node_kernel(
    const float* __restrict__ nf, const float* __restrict__ attrs,
    const float* __restrict__ l1w0, const float* __restrict__ l1w1,
    const float* __restrict__ scw0, const float* __restrict__ scw1,
    float* __restrict__ h4, float* __restrict__ out) {
    int n = blockIdx.x;
    int t = threadIdx.x;
    __shared__ float x[128];
    __shared__ int vs;
    x[t] = nf[n * 128 + t];
    if (t < 16) {
        if (attrs[n * 16 + t] > 0.5f) vs = t;   // one-hot: exactly one writer
    }
    __syncthreads();
    int v = vs;
    if (t < 32) {
        int w = t;
        float a = 0.f, b = 0.f;
        #pragma unroll
        for (int u = 0; u < 32; ++u) {
            float xv = x[u];
            a = fmaf(xv, l1w0[u * 32 + w], a);
            b = fmaf(xv, scw0[u * 512 + v * 32 + w], b);
        }
        h4[n * 128 + w * 4] = a * H_SCALE;
        out[n * 128 + w]    = b * FAN_SC;
    } else {
        int j = t - 32;                // 0..95
        int vch = j / 3, m = j - vch * 3;
        float a = 0.f, b = 0.f;
        #pragma unroll
        for (int u = 0; u < 32; ++u) {
            float xv = x[32 + u * 3 + m];
            a = fmaf(xv, l1w1[u * 32 + vch], a);
            b = fmaf(xv, scw1[u * 512 + v * 32 + vch], b);
        }
        h4[n * 128 + vch * 4 + 1 + m]   = a * H_SCALE;
        out[n * 128 + 32 + vch * 3 + m] = b * FAN_SC;
    }
}

// ---------------- FUSED edge kernel: layer1 VALU + layer2 MFMA + window reduce ----
// block = 256 threads = 4 waves = 4 windows of 64 sorted edges. Wave wid's lanes
// hold exactly its window's edges (tid = wid*64 + t). MFMA output goes to a
// per-wave LDS strip (2 passes of 32 edges); the same wave then runs the
// windowed segmented reduction, reading w from LDS, broadcasting eattr/src/dst
// from lane registers via readlane. No rec buffer, no cross-wave traffic.
__global__ __launch_bounds__(256) void fused_kernel(
    const float* __restrict__ ee, const float4* __restrict__ eattr4,
    const int* __restrict__ order, const int* __restrict__ srcs,
    const int* __restrict__ dsts, const int* __restrict__ off,
    const float* __restrict__ w0, const float* __restrict__ w1,
    const float4* __restrict__ h4, float* __restrict__ mn,
    float* __restrict__ sb, int len) {
    __shared__ unsigned amat[256 * 32];        // 32 KB: [edge][64 bf16], XOR-swizzled
    __shared__ unsigned wlds[4][32][66];       // 33.8 KB: per-wave pass buffer
    int tid  = threadIdx.x;
    int t    = tid & 63, wid = tid >> 6;
    int m = t & 15, q = t >> 4;
    int gidx = blockIdx.x * 256 + tid;
    bool valid = gidx < len;

    // ---- B fragments for ALL 4 strips (64 VGPRs): bf16(w1[k][chan])
    short8 bfL0[4], bfL1[4], bfH0[4], bfH1[4];
    #pragma unroll
    for (int s = 0; s < 4; ++s) {
        int clo = s * 16 + m, chi = clo + 64;
        short8 l0, l1, h0, h1;
        #pragma unroll
        for (int i = 0; i < 8; ++i) {
            int k0 = q * 8 + i, k1 = 32 + q * 8 + i;
            l0[i] = bf16b(w1[k0 * 128 + clo]);
            l1[i] = bf16b(w1[k1 * 128 + clo]);
            h0[i] = bf16b(w1[k0 * 128 + chi]);
            h1[i] = bf16b(w1[k1 * 128 + chi]);
        }
        bfL0[s] = l0; bfL1[s] = l1; bfH0[s] = h0; bfH1[s] = h1;
    }

    // ---- per-edge loads (this thread = this edge of its wave's window)
    float4 eat = make_float4(0.f, 0.f, 0.f, 0.f);
    float eev[8] = {0.f,0.f,0.f,0.f,0.f,0.f,0.f,0.f};
    int src_t = 0, dst_t = -1;
    if (valid) {
        int e = order[gidx];
        eat = eattr4[e];
        src_t = srcs[gidx];
        dst_t = dsts[gidx];
        const float4* eep = (const float4*)ee;
        float4 e0 = eep[(size_t)e * 2], e1 = eep[(size_t)e * 2 + 1];
        eev[0] = e0.x * SQRT8_INV; eev[1] = e0.y * SQRT8_INV;
        eev[2] = e0.z * SQRT8_INV; eev[3] = e0.w * SQRT8_INV;
        eev[4] = e1.x * SQRT8_INV; eev[5] = e1.y * SQRT8_INV;
        eev[6] = e1.z * SQRT8_INV; eev[7] = e1.w * SQRT8_INV;
    }

    // ---- layer 1 + silu in chunks of 8, pack + stage into amat
    {
        char* arow = (char*)(amat + tid * 32);
        #pragma unroll
        for (int kc = 0; kc < 8; ++kc) {
            float h[8];
            #pragma unroll
            for (int jj = 0; jj < 8; ++jj) {
                int j = kc * 8 + jj;
                float a = 0.f;
                #pragma unroll
                for (int k = 0; k < 8; ++k) a = fmaf(eev[k], w0[k * 64 + j], a);
                float s = 1.f / (1.f + __expf(-a));
                h[jj] = a * s * W1_SCALE;
            }
            uint4 v = make_uint4(pack_bf16(h[0], h[1]), pack_bf16(h[2], h[3]),
                                 pack_bf16(h[4], h[5]), pack_bf16(h[6], h[7]));
            if (!valid) v = make_uint4(0u, 0u, 0u, 0u);
            *(uint4*)(arow + ((kc * 16) ^ ((tid & 7) << 4))) = v;
        }
    }
    __syncthreads();   // amat visible (also the last barrier — waves diverge below)

    int gbeg = blockIdx.x * 256 + wid * 64;
    if (gbeg >= len) return;
    int cnt  = min(64, len - gbeg);
    int gend = gbeg + cnt;
    int gwin = gbeg >> 6;
    int c = t & 31, half = t >> 5;
    int kk = half ? c + 32 : c;

    // boundary mask for this window (one ballot)
    int nxt = __shfl_down(dst_t, 1);
    bool bnd = (t < cnt) && ((t == cnt - 1) || (dst_t != nxt));
    unsigned long long bmask = __ballot(bnd);

    float acc0 = 0.f, acc1 = 0.f, acc2 = 0.f, acc3 = 0.f;

#define REFILL(k, jj) do {                                                    \
        int _j = (jj);                                                        \
        if (_j < jend) {                                                      \
            wu##k = wlds[wid][_j & 31][kk];                                   \
            int _s = __builtin_amdgcn_readlane(src_t, _j);                    \
            xs##k = h4[(size_t)_s * 32 + c];                                  \
            ea##k.x = __uint_as_float(__builtin_amdgcn_readlane(__float_as_uint(eat.x), _j)); \
            ea##k.y = __uint_as_float(__builtin_amdgcn_readlane(__float_as_uint(eat.y), _j)); \
            ea##k.z = __uint_as_float(__builtin_amdgcn_readlane(__float_as_uint(eat.z), _j)); \
            ea##k.w = __uint_as_float(__builtin_amdgcn_readlane(__float_as_uint(eat.w), _j)); \
        }                                                                     \
    } while (0)

#define COMPUTE(k) do {                                                 \
        float wlo = bf_lo(wu##k), whi = bf_hi(wu##k);                   \
        float4 _ea = ea##k, _xs = xs##k;                                \
        if (half == 0) {                                                \
            acc0 = fmaf(wlo * _xs.x, _ea.x, acc0);       /* m0a */      \
            float cy = whi * _ea.x;                                     \
            acc1 = fmaf(cy, _xs.y, acc1);                /* m1b */      \
            acc2 = fmaf(cy, _xs.z, acc2);                               \
            acc3 = fmaf(cy, _xs.w, acc3);                               \
        } else {                                                        \
            float bx = wlo * _xs.x;                                     \
            acc1 = fmaf(bx, _ea.y, acc1);                /* m1a */      \
            acc2 = fmaf(bx, _ea.z, acc2);                               \
            acc3 = fmaf(bx, _ea.w, acc3);                               \
            float dv = _xs.y * _ea.y + _xs.z * _ea.z + _xs.w * _ea.w;   \
            acc0 = fmaf(whi * SQ3_INVF, dv, acc0);       /* m0b */      \
        }                                                               \
    } while (0)

#define FLUSH(jj) do {                                                  \
        int _n = __builtin_amdgcn_readlane(dst_t, (jj));                \
        bool _cs = off[_n] < gbeg;                                      \
        bool _ce = off[_n + 1] > gend;                                  \
        float* _dp = (!_cs && !_ce) ? (mn + (size_t)_n * 256)           \
                   : (sb + ((size_t)gwin * 2 + (_cs ? 0 : 1)) * 256);   \
        if (half == 0) {                                                \
            _dp[c] = acc0;                                              \
            _dp[160 + 3*c + 0] = acc1;                                  \
            _dp[160 + 3*c + 1] = acc2;                                  \
            _dp[160 + 3*c + 2] = acc3;                                  \
        } else {                                                        \
            _dp[32 + c] = acc0;                                         \
            _dp[64 + 3*c + 0] = acc1;                                   \
            _dp[64 + 3*c + 1] = acc2;                                   \
            _dp[64 + 3*c + 2] = acc3;                                   \
        }                                                               \
        acc0 = acc1 = acc2 = acc3 = 0.f;                                \
    } while (0)

    #pragma unroll
    for (int p = 0; p < 2; ++p) {
        if (p * 32 >= cnt) break;

        // ---- MFMA for this pass's 2 edge-tiles; w-words -> per-wave LDS
        #pragma unroll
        for (int u = 0; u < 2; ++u) {
            int et = 2 * p + u;
            int row = wid * 64 + et * 16 + m;
            const char* abase = (const char*)(amat + row * 32);
            int swz = (row & 7) << 4;
            short8 a0 = *(const short8*)(abase + ((q * 16) ^ swz));
            short8 a1 = *(const short8*)(abase + ((64 + q * 16) ^ swz));
            #pragma unroll
            for (int s = 0; s < 4; ++s) {
                f32x4 dlo = {0.f,0.f,0.f,0.f}, dhi = {0.f,0.f,0.f,0.f};
                dlo = __builtin_amdgcn_mfma_f32_16x16x32_bf16(a0, bfL0[s], dlo, 0, 0, 0);
                dlo = __builtin_amdgcn_mfma_f32_16x16x32_bf16(a1, bfL1[s], dlo, 0, 0, 0);
                dhi = __builtin_amdgcn_mfma_f32_16x16x32_bf16(a0, bfH0[s], dhi, 0, 0, 0);
                dhi = __builtin_amdgcn_mfma_f32_16x16x32_bf16(a1, bfH1[s], dhi, 0, 0, 0);
                #pragma unroll
                for (int i = 0; i < 4; ++i)
                    wlds[wid][u * 16 + 4 * q + i][s * 16 + m] = pack_bf16(dlo[i], dhi[i]);
            }
        }
        // intra-wave ds write->read: program order + lgkmcnt suffices (no barrier)

        // ---- windowed segmented reduce over this pass's edges
        int jbeg = p * 32, jend = min(cnt, p * 32 + 32);
        unsigned wu0 = 0, wu1 = 0, wu2 = 0, wu3 = 0;
        float4 ea0 = make_float4(0,0,0,0), ea1 = ea0, ea2 = ea0, ea3 = ea0;
        float4 xs0 = ea0, xs1 = ea0, xs2 = ea0, xs3 = ea0;
        REFILL(0, jbeg); REFILL(1, jbeg + 1); REFILL(2, jbeg + 2); REFILL(3, jbeg + 3);
        int j = jbeg;
        for (; j + 4 <= jend; j += 4) {
            COMPUTE(0); if ((bmask >> (j + 0)) & 1) FLUSH(j + 0); REFILL(0, j + 4);
            COMPUTE(1); if ((bmask >> (j + 1)) & 1) FLUSH(j + 1); REFILL(1, j + 5);
            COMPUTE(2); if ((bmask >> (j + 2)) & 1) FLUSH(j + 2); REFILL(2, j + 6);
            COMPUTE(3); if ((bmask >> (j + 3)) & 1) FLUSH(j + 3); REFILL(3, j + 7);
        }
        int rem = jend - j;
        if (rem > 0) { COMPUTE(0); if ((bmask >> (j + 0)) & 1) FLUSH(j + 0); }
        if (rem > 1) { COMPUTE(1); if ((bmask >> (j + 1)) & 1) FLUSH(j + 1); }
        if (rem > 2) { COMPUTE(2); if ((bmask >> (j + 2)) & 1) FLUSH(j + 2); }
    }
#undef REFILL
#undef COMPUTE
#undef FLUSH
}

// ---------------- fixup + lin2: combine mn / sideband partials, write out ----------
__global__ __launch_bounds__(256) void fixlin_kernel(
    const float* __restrict__ mn, const float* __restrict__ sb,
    const int* __restrict__ off,
    const float* __restrict__ l2w0, const float* __restrict__ l2w1,
    float* __restrict__ out, int N) {
    int w = threadIdx.x >> 6, t = threadIdx.x & 63;
    int n = blockIdx.x * 4 + w;
    __shared__ float ld[4][256];
    int c = t & 31, half = t >> 5;
    bool has = false;
    if (n < N) {
        int b = off[n], e = off[n + 1];
        if (e > b) {
            has = true;
            int w0 = b >> 6, w1 = (e - 1) >> 6;
            int p0 = half ? 32 + c : c;
            int p1 = half ? 64 + 3 * c : 160 + 3 * c;
            float v0, v1, v2, v3;
            if (w0 == w1) {
                const float* r = mn + (size_t)n * 256;   // interior: direct row
                v0 = r[p0]; v1 = r[p1]; v2 = r[p1 + 1]; v3 = r[p1 + 2];
            } else {
                const float* r = sb + ((size_t)w0 * 2 + 1) * 256;  // tail of w0
                v0 = r[p0]; v1 = r[p1]; v2 = r[p1 + 1]; v3 = r[p1 + 2];
                for (int ww = w0 + 1; ww <= w1; ++ww) {            // slot0 of rest
                    const float* qq = sb + ((size_t)ww * 2) * 256;
                    v0 += qq[p0]; v1 += qq[p1]; v2 += qq[p1 + 1]; v3 += qq[p1 + 2];
                }
            }
            ld[w][p0] = v0;
            ld[w][p1] = v1; ld[w][p1 + 1] = v2; ld[w][p1 + 2] = v3;
        }
    }
    __syncthreads();
    if (n < N && has) {
        #pragma unroll
        for (int hh = 0; hh < 2; ++hh) {
            int j = t + hh * 64;
            float acc = 0.f;
            if (j < 32) {
                #pragma unroll
                for (int u = 0; u < 64; ++u) acc = fmaf(ld[w][u], l2w0[u * 32 + j], acc);
            } else {
                int jj = j - 32, vch = jj / 3, m = jj - vch * 3;
                #pragma unroll
                for (int u = 0; u < 64; ++u) acc = fmaf(ld[w][64 + u * 3 + m], l2w1[u * 32 + vch], acc);
            }
            out[(size_t)n * 128 + j] += acc * LIN2_SCALE;
        }
    }
}

// ---------------- FALLBACK (ws too small): round-2 fused gather ----------------
__global__ __launch_bounds__(64) void gather_kernel(
    const float* __restrict__ ee, const float4* __restrict__ eattr4,
    const int* __restrict__ eidx, const int* __restrict__ order,
    const int* __restrict__ off,
    const float* __restrict__ w0, const float2* __restrict__ w1p2,
    const float4* __restrict__ h4,
    const float* __restrict__ l2w0, const float* __restrict__ l2w1,
    float* __restrict__ out, int E) {
    int n = blockIdx.x, t = threadIdx.x;
    int beg = off[n], end = off[n + 1];
    __shared__ float s_ee[8];
    __shared__ float s_hid[64];
    __shared__ float ld[256];
    float acc0 = 0.f, acc1 = 0.f, acc2 = 0.f, acc3 = 0.f;
    int c = t & 31;
    for (int i = beg; i < end; ++i) {
        int e = order[i];
        int src = eidx[E + e];
        if (t < 8) s_ee[t] = ee[e * 8 + t] * SQRT8_INV;
        __syncthreads();
        float a = 0.f;
        #pragma unroll
        for (int k = 0; k < 8; ++k) a = fmaf(s_ee[k], w0[k * 64 + t], a);
        float sg = 1.f / (1.f + __expf(-a));
        __syncthreads();
        s_hid[t] = a * sg * W1_SCALE;
        __syncthreads();
        float wA = 0.f, wB = 0.f;
        #pragma unroll
        for (int j = 0; j < 64; ++j) {
            float2 wv = w1p2[j * 64 + t];
            float hj = s_hid[j];
            wA = fmaf(hj, wv.x, wA);
            wB = fmaf(hj, wv.y, wB);
        }
        float4 xs = h4[(size_t)src * 32 + c];
        float4 ea = eattr4[e];
        if (t < 32) {
            acc0 = fmaf(wA * xs.x, ea.x, acc0);
            float bx = wB * xs.x;
            acc1 = fmaf(bx, ea.y, acc1);
            acc2 = fmaf(bx, ea.z, acc2);
            acc3 = fmaf(bx, ea.w, acc3);
        } else {
            float dv = xs.y * ea.y + xs.z * ea.z + xs.w * ea.w;
            acc0 = fmaf(wB * SQ3_INVF, dv, acc0);
            float cy = wA * ea.x;
            acc1 = fmaf(cy, xs.y, acc1);
            acc2 = fmaf(cy, xs.z, acc2);
            acc3 = fmaf(cy, xs.w, acc3);
        }
    }
    if (t < 32) {
        ld[t] = acc0;
        ld[64 + t * 3 + 0] = acc1;
        ld[64 + t * 3 + 1] = acc2;
        ld[64 + t * 3 + 2] = acc3;
    } else {
        int cc = t - 32;
        ld[32 + cc] = acc0;
        ld[160 + cc * 3 + 0] = acc1;
        ld[160 + cc * 3 + 1] = acc2;
        ld[160 + cc * 3 + 2] = acc3;
    }
    __syncthreads();
    #pragma unroll
    for (int hh = 0; hh < 2; ++hh) {
        int j = t + hh * 64;
        float acc = 0.f;
        if (j < 32) {
            #pragma unroll
            for (int u = 0; u < 64; ++u) acc = fmaf(ld[u], l2w0[u * 32 + j], acc);
        } else {
            int jj = j - 32, vch = jj / 3, m = jj - vch * 3;
            #pragma unroll
            for (int u = 0; u < 64; ++u) acc = fmaf(ld[64 + u * 3 + m], l2w1[u * 32 + vch], acc);
        }
        out[(size_t)n * 128 + j] += acc * LIN2_SCALE;
    }
}

extern "C" void kernel_launch(void* const* d_in, const int* in_sizes, int n_in,
                              void* d_out, int out_size, void* d_ws, size_t ws_size,
                              hipStream_t stream) {
    const float* nf    = (const float*)d_in[0];
    const float* attrs = (const float*)d_in[1];
    const float* eattr = (const float*)d_in[2];
    const float* ee    = (const float*)d_in[3];
    const int*   eidx  = (const int*)d_in[4];
    const float* l1w0  = (const float*)d_in[5];
    const float* l1w1  = (const float*)d_in[6];
    const float* w0    = (const float*)d_in[7];
    const float* w1    = (const float*)d_in[8];
    const float* l2w0  = (const float*)d_in[9];
    const float* l2w1  = (const float*)d_in[10];
    const float* scw0  = (const float*)d_in[11];
    const float* scw1  = (const float*)d_in[12];

    int N = in_sizes[0] / 128;
    int E = in_sizes[3] / 8;
    int nb = (N + 255) / 256;
    int nw = (E + 63) / 64;

    // ws layout: h4 | w1p | cnt | off | cur | bsum | order | srcs | dsts | mn | sb
    float* h4    = (float*)d_ws;                       // N*128
    float* w1p   = h4 + (size_t)N * 128;               // 8192
    int*   cnt   = (int*)(w1p + 8192);                 // N
    int*   off   = cnt + N;                            // N+1
    int*   cur   = off + N + 1;                        // N
    int*   bsum  = cur + N;                            // nb
    int*   order = bsum + nb;                          // E
    int*   srcs  = order + E;                          // E
    int*   dsts  = srcs + E;                           // E
    float* mn    = (float*)(dsts + E);                 // N*256
    float* sb    = mn + (size_t)N * 256;               // nw*512
    size_t need  = (size_t)((char*)(sb + (size_t)nw * 512) - (char*)d_ws);
    bool big = ws_size >= need;

    zero_int<<<(N + 255) / 256, 256, 0, stream>>>(cnt, N);
    hist_kernel<<<(E + 255) / 256, 256, 0, stream>>>(eidx, cnt, E);
    scan_bsum<<<nb, 256, 0, stream>>>(cnt, bsum, N);
    scan_bscan<<<1, 1024, 0, stream>>>(bsum, nb);
    scan_final<<<nb, 256, 0, stream>>>(cnt, bsum, off, cur, N);
    scatter_kernel<<<(E + 255) / 256, 256, 0, stream>>>(eidx, cur, order, srcs, dsts, E);
    node_kernel<<<N, 128, 0, stream>>>(nf, attrs, l1w0, l1w1, scw0, scw1, h4, (float*)d_out);

    if (big) {
        fused_kernel<<<(E + 255) / 256, 256, 0, stream>>>(ee, (const float4*)eattr,
                                                          order, srcs, dsts, off,
                                                          w0, w1, (const float4*)h4,
                                                          mn, sb, E);
        fixlin_kernel<<<(N + 3) / 4, 256, 0, stream>>>(mn, sb, off, l2w0, l2w1,
                                                       (float*)d_out, N);
    } else {
        prep_w1p<<<16, 256, 0, stream>>>(w1, w1p);
        gather_kernel<<<N, 64, 0, stream>>>(ee, (const float4*)eattr, eidx, order, off,
                                            w0, (const float2*)w1p, (const float4*)h4,
                                            l2w0, l2w1, (float*)d_out, E);
    }
}